// Round 4
// baseline (184.857 us; speedup 1.0000x reference)
//
#include <hip/hip_runtime.h>
#include <math.h>

#define VOCAB 2048
#define TPB   256
#define WPB   4            // waves per block; each wave owns 2 consecutive rows
#define NBINS 64
// 64 bins cover (m - v) in [0, 64/6 = 10.667); kept tokens provably have
// m - v <= ln(2048/0.05) = 10.62, so the top-p crossing is always inside.
#define BIN_SCALE 6.0f
#define CAP   256          // compaction capacity per wave (boundary & kept)

typedef float vf4 __attribute__((ext_vector_type(4)));

// Depth-2 REGISTER pipeline, zero barriers, zero manual waitcnt.
// Both rows' 16 global loads are issued up front as 16 *named* vf4 regs
// (no buffer arrays, no select between buffers -> nothing can go to
// scratch, unlike R2). The compiler's counted vmcnt lets row 0's compute
// begin while row 1's 8 loads remain in flight, so HBM demand persists
// through the compute phase instead of the lockstep burst/idle pattern.
__global__ __launch_bounds__(TPB, 4) void sampler_kernel(
    const float* __restrict__ logits,
    const float* __restrict__ uni,
    float* __restrict__ out_idx,    // [B]   sampled index as float
    float* __restrict__ out_probs)  // [B,V] filtered softmax
{
    const int lane = threadIdx.x & 63;
    const int wid  = threadIdx.x >> 6;
    const int r0   = (blockIdx.x * WPB + wid) * 2;

    __shared__ float s_bins[WPB][NBINS];
    __shared__ float s_cv[WPB][CAP];   // phase A: boundary values; phase B: kept values
    __shared__ float s_ci[WPB][CAP];   // phase A: boundary exps;   phase B: kept idx (bits)
    __shared__ int   s_bcnt[WPB];
    __shared__ int   s_kcnt[WPB];

    const float* L = logits + (size_t)r0 * VOCAB;

    // ---- issue ALL 16 loads (both rows) as named registers ----
    vf4 a0 = __builtin_nontemporal_load((const vf4*)(L +    0 + 4 * lane));
    vf4 a1 = __builtin_nontemporal_load((const vf4*)(L +  256 + 4 * lane));
    vf4 a2 = __builtin_nontemporal_load((const vf4*)(L +  512 + 4 * lane));
    vf4 a3 = __builtin_nontemporal_load((const vf4*)(L +  768 + 4 * lane));
    vf4 a4 = __builtin_nontemporal_load((const vf4*)(L + 1024 + 4 * lane));
    vf4 a5 = __builtin_nontemporal_load((const vf4*)(L + 1280 + 4 * lane));
    vf4 a6 = __builtin_nontemporal_load((const vf4*)(L + 1536 + 4 * lane));
    vf4 a7 = __builtin_nontemporal_load((const vf4*)(L + 1792 + 4 * lane));
    vf4 c0 = __builtin_nontemporal_load((const vf4*)(L + VOCAB +    0 + 4 * lane));
    vf4 c1 = __builtin_nontemporal_load((const vf4*)(L + VOCAB +  256 + 4 * lane));
    vf4 c2 = __builtin_nontemporal_load((const vf4*)(L + VOCAB +  512 + 4 * lane));
    vf4 c3 = __builtin_nontemporal_load((const vf4*)(L + VOCAB +  768 + 4 * lane));
    vf4 c4 = __builtin_nontemporal_load((const vf4*)(L + VOCAB + 1024 + 4 * lane));
    vf4 c5 = __builtin_nontemporal_load((const vf4*)(L + VOCAB + 1280 + 4 * lane));
    vf4 c6 = __builtin_nontemporal_load((const vf4*)(L + VOCAB + 1536 + 4 * lane));
    vf4 c7 = __builtin_nontemporal_load((const vf4*)(L + VOCAB + 1792 + 4 * lane));

    auto process_row = [&](int row, vf4 v0, vf4 v1, vf4 v2, vf4 v3,
                           vf4 v4, vf4 v5, vf4 v6, vf4 v7) {
        const float* urow = uni       + (size_t)row * VOCAB;
        float*       prow = out_probs + (size_t)row * VOCAB;

        // wave-private LDS init (same-wave DS ordering: no barrier needed)
        s_bins[wid][lane] = 0.0f;
        if (lane == 0) { s_bcnt[wid] = 0; s_kcnt[wid] = 0; }

        // ---- temperature scale (x*1.25f ~ x/0.8f to ~1 ulp) ----
        float s[32];
#define UNPACK(k, vv) s[4*(k)+0] = (vv).x * 1.25f; s[4*(k)+1] = (vv).y * 1.25f; \
                      s[4*(k)+2] = (vv).z * 1.25f; s[4*(k)+3] = (vv).w * 1.25f;
        UNPACK(0, v0) UNPACK(1, v1) UNPACK(2, v2) UNPACK(3, v3)
        UNPACK(4, v4) UNPACK(5, v5) UNPACK(6, v6) UNPACK(7, v7)
#undef UNPACK

        // ---- wave max (butterfly -> all lanes) ----
        float m0 = s[0], m1 = s[1], m2 = s[2], m3 = s[3];
        #pragma unroll
        for (int j = 4; j < 32; j += 4) {
            m0 = fmaxf(m0, s[j+0]); m1 = fmaxf(m1, s[j+1]);
            m2 = fmaxf(m2, s[j+2]); m3 = fmaxf(m3, s[j+3]);
        }
        float m = fmaxf(fmaxf(m0, m1), fmaxf(m2, m3));
        #pragma unroll
        for (int off = 32; off; off >>= 1)
            m = fmaxf(m, __shfl_xor(m, off));

        // ---- exp (fast), total sum (double), exp-mass histogram by value bin ----
        double p0 = 0.0, p1 = 0.0;
        #pragma unroll
        for (int j = 0; j < 32; j++) {
            float e = __expf(s[j] - m);
            if (j & 1) p1 += (double)e; else p0 += (double)e;
            int bb = (int)((m - s[j]) * BIN_SCALE);
            if (bb < NBINS) atomicAdd(&s_bins[wid][bb], e);
        }
        double dp = p0 + p1;
        #pragma unroll
        for (int off = 32; off; off >>= 1)
            dp += __shfl_xor(dp, off);
        const double pS = 0.95 * dp;

        // ---- in-wave prefix scan of the 64 bins (1 bin per lane) ----
        const float bf = s_bins[wid][lane];   // same-wave DS order: atomics done
        double c = (double)bf;
        #pragma unroll
        for (int d = 1; d < 64; d <<= 1) {
            double o = __shfl_up(c, d);
            if (lane >= d) c += o;
        }
        const unsigned long long ball = __ballot(c > pS);
        const int bstar = ball ? (__ffsll(ball) - 1) : (NBINS - 1);
        double excl = c - (double)bf;         // exclusive prefix
        const double cumBefore = __shfl(excl, bstar);

        // ---- compact boundary-bin candidates (value, exp) to wave LDS ----
        #pragma unroll
        for (int j = 0; j < 32; j++) {
            int bb = (int)((m - s[j]) * BIN_SCALE);
            if (bb == bstar) {
                int pos = atomicAdd(&s_bcnt[wid], 1);
                if (pos < CAP) {
                    s_cv[wid][pos] = s[j];
                    s_ci[wid][pos] = __expf(s[j] - m);
                }
            }
        }
        const int bcnt = min(s_bcnt[wid], CAP);

        // ---- keep decision: kept <=> exp-sum over strictly-greater <= p*S ----
        // SK (kept mass) = cumBefore (all bins < bstar kept) + boundary-kept sum.
        unsigned keptMask = 0;
        float bk = 0.0f;
        #pragma unroll
        for (int j = 0; j < 32; j++) {
            int bb = (int)((m - s[j]) * BIN_SCALE);
            bool kept;
            if (bb < bstar)      kept = true;
            else if (bb > bstar) kept = false;
            else {
                float part = 0.0f;
                for (int i = 0; i < bcnt; i++)
                    if (s_cv[wid][i] > s[j]) part += s_ci[wid][i];  // broadcast reads
                kept = (cumBefore + (double)part) <= pS;
                if (kept) bk += __expf(s[j] - m);
            }
            if (kept) keptMask |= (1u << j);
        }
        #pragma unroll
        for (int off = 32; off; off >>= 1)
            bk += __shfl_xor(bk, off);
        const float invSK = 1.0f / (float)(cumBefore + (double)bk);

        // ---- write probs (nontemporal: never re-read) ----
        #pragma unroll
        for (int j = 0; j < 8; j++) {
            vf4 p;
            p.x = ((keptMask >> (4*j+0)) & 1u) ? __expf(s[4*j+0] - m) * invSK : 0.0f;
            p.y = ((keptMask >> (4*j+1)) & 1u) ? __expf(s[4*j+1] - m) * invSK : 0.0f;
            p.z = ((keptMask >> (4*j+2)) & 1u) ? __expf(s[4*j+2] - m) * invSK : 0.0f;
            p.w = ((keptMask >> (4*j+3)) & 1u) ? __expf(s[4*j+3] - m) * invSK : 0.0f;
            __builtin_nontemporal_store(p, (vf4*)(prow + j * 256 + 4 * lane));
        }

        // ---- compact KEPT tokens (value, idx); in-register fallback on overflow ----
        unsigned ovf = 0;
        #pragma unroll
        for (int j = 0; j < 32; j++) {
            if ((keptMask >> j) & 1u) {
                int pos = atomicAdd(&s_kcnt[wid], 1);
                if (pos < CAP) {
                    s_cv[wid][pos] = s[j];
                    s_ci[wid][pos] = __int_as_float((j >> 2) * 256 + 4 * lane + (j & 3));
                } else {
                    ovf |= (1u << j);
                }
            }
        }
        const int kc = min(s_kcnt[wid], CAP);

        // ---- Gumbel-max over kept tokens (precise logf, sparse u gather) ----
        unsigned long long key = 0ull;   // any real z maps above 0
        for (int i = lane; i < kc; i += 64) {
            float sv  = s_cv[wid][i];
            int   idx = __float_as_int(s_ci[wid][i]);
            float uv  = urow[idx];
            float g   = -logf(-logf(uv));
            float z   = sv + g;
            unsigned zb = __float_as_uint(z);
            zb = (zb & 0x80000000u) ? ~zb : (zb | 0x80000000u);  // order-preserving map
            unsigned long long kk =
                ((unsigned long long)zb << 32) | (unsigned)(VOCAB - 1 - idx); // min-idx tiebreak
            key = (kk > key) ? kk : key;
        }
        if (__builtin_expect(ovf != 0, 0)) {  // cold exact path: row had >CAP kept
            #pragma unroll
            for (int j = 0; j < 32; j++) {
                if ((ovf >> j) & 1u) {
                    int   idx = (j >> 2) * 256 + 4 * lane + (j & 3);
                    float uv  = urow[idx];
                    float g   = -logf(-logf(uv));
                    float z   = s[j] + g;
                    unsigned zb = __float_as_uint(z);
                    zb = (zb & 0x80000000u) ? ~zb : (zb | 0x80000000u);
                    unsigned long long kk =
                        ((unsigned long long)zb << 32) | (unsigned)(VOCAB - 1 - idx);
                    key = (kk > key) ? kk : key;
                }
            }
        }
        #pragma unroll
        for (int off = 32; off; off >>= 1) {
            unsigned long long ok = __shfl_xor(key, off);
            key = (ok > key) ? ok : key;
        }
        if (lane == 0)
            out_idx[row] = (float)(VOCAB - 1 - (int)(key & 0xFFFFFFFFu));
    };

    // row 0 computes while row 1's loads are still in flight (counted vmcnt)
    process_row(r0,     a0, a1, a2, a3, a4, a5, a6, a7);
    process_row(r0 + 1, c0, c1, c2, c3, c4, c5, c6, c7);
}

extern "C" void kernel_launch(void* const* d_in, const int* in_sizes, int n_in,
                              void* d_out, int out_size, void* d_ws, size_t ws_size,
                              hipStream_t stream) {
    const float* logits = (const float*)d_in[0];
    const float* u      = (const float*)d_in[1];
    const int B = in_sizes[0] / VOCAB;   // 8192
    float* out_idx   = (float*)d_out;          // sampled [B,1] flattened
    float* out_probs = (float*)d_out + B;      // probs [B,V]
    sampler_kernel<<<B / (WPB * 2), TPB, 0, stream>>>(logits, u, out_idx, out_probs);
}